// Round 1
// baseline (465.671 us; speedup 1.0000x reference)
//
#include <hip/hip_runtime.h>

// MultiTaskLoss: N=8, C=19, H=512, W=1024, fp32.
// Inputs (d_in order): loss_weight[19], masks_pred[N,C,H,W], deps_pred[N,1,H,W],
//                      true_masks[N,H,W] (int32), true_deps[N,1,H,W]
// Output: single fp32 scalar (= loss_seg/loss_seg + loss_dep/loss_dep == 2.0 analytically,
// but computed honestly from the data).

constexpr int kN = 8;
constexpr int kC = 19;
constexpr int kH = 512;
constexpr int kW = 1024;
constexpr int kHW = kH * kW;        // 524288 = 2^19
constexpr int kNHW = kN * kHW;      // 4194304
constexpr int kQuads = kNHW / 4;    // 1048576
constexpr int kLogHW = 19;          // log2(kHW)

// ws layout in 32-bit words: [0..18] seg_sum (float), [19..37] argmax counts (uint32),
// [38] dep_sum (float). Total 39 words = 156 bytes.
constexpr int WS_SEG = 0;
constexpr int WS_CNT = kC;
constexpr int WS_DEP = 2 * kC;

__global__ __launch_bounds__(256) void mtl_main(
    const float* __restrict__ masks,   // [N,C,H,W]
    const float* __restrict__ deps,    // [N,1,H,W]
    const int*   __restrict__ tmasks,  // [N,H,W]
    const float* __restrict__ tdeps,   // [N,1,H,W]
    float* __restrict__ ws)
{
    __shared__ float    s_seg[kC];
    __shared__ unsigned s_cnt[kC];
    __shared__ float    s_dep;

    const int tid = threadIdx.x;
    if (tid < kC) { s_seg[tid] = 0.0f; s_cnt[tid] = 0u; }
    if (tid == 0) s_dep = 0.0f;
    __syncthreads();

    float dep_acc = 0.0f;
    const int stride = gridDim.x * blockDim.x;

    for (int q = blockIdx.x * blockDim.x + tid; q < kQuads; q += stride) {
        const int p   = q << 2;            // pixel index, multiple of 4 (16B aligned)
        const int n   = p >> kLogHW;       // image index
        const int rem = p & (kHW - 1);     // offset within image

        // Base for this image's channel-major block; channel stride = kHW floats.
        const float4* mb = reinterpret_cast<const float4*>(
            masks + (size_t)n * kC * kHW + rem);

        // Transposed register tile: 4 pixels x 19 channels.
        float x0[kC], x1[kC], x2[kC], x3[kC];
#pragma unroll
        for (int c = 0; c < kC; ++c) {
            float4 v = mb[(size_t)c * (kHW / 4)];
            x0[c] = v.x; x1[c] = v.y; x2[c] = v.z; x3[c] = v.w;
        }

        const int4   tm = *reinterpret_cast<const int4*>(tmasks + p);
        const float4 dp = *reinterpret_cast<const float4*>(deps + p);
        const float4 td = *reinterpret_cast<const float4*>(tdeps + p);
        dep_acc += fabsf(dp.x - td.x) + fabsf(dp.y - td.y) +
                   fabsf(dp.z - td.z) + fabsf(dp.w - td.w);

        // Per-pixel: max+argmax (first-occurrence), logsumexp, CE at true class,
        // LDS histogram accumulate.
#define PIXEL(XARR, TMJ)                                                \
        {                                                               \
            float mx = XARR[0]; int amx = 0;                            \
            _Pragma("unroll")                                           \
            for (int c = 1; c < kC; ++c) {                              \
                if (XARR[c] > mx) { mx = XARR[c]; amx = c; }            \
            }                                                           \
            float se = 0.0f, xt = 0.0f;                                 \
            _Pragma("unroll")                                           \
            for (int c = 0; c < kC; ++c) {                              \
                se += __expf(XARR[c] - mx);                             \
                xt = (c == (TMJ)) ? XARR[c] : xt;                       \
            }                                                           \
            float loss = mx + __logf(se) - xt;                          \
            atomicAdd(&s_seg[amx], loss);                               \
            atomicAdd(&s_cnt[amx], 1u);                                 \
        }

        PIXEL(x0, tm.x)
        PIXEL(x1, tm.y)
        PIXEL(x2, tm.z)
        PIXEL(x3, tm.w)
#undef PIXEL
    }

    // Block-level dep reduction: wave shuffle, then LDS atomic, then global.
#pragma unroll
    for (int off = 32; off > 0; off >>= 1)
        dep_acc += __shfl_down(dep_acc, off, 64);
    if ((tid & 63) == 0) atomicAdd(&s_dep, dep_acc);
    __syncthreads();

    if (tid < kC) {
        atomicAdd(&ws[WS_SEG + tid], s_seg[tid]);
        atomicAdd(reinterpret_cast<unsigned*>(ws) + WS_CNT + tid, s_cnt[tid]);
    }
    if (tid == 0) atomicAdd(&ws[WS_DEP], s_dep);
}

__global__ __launch_bounds__(64) void mtl_final(
    const float* __restrict__ lw,   // loss_weight[19]
    const float* __restrict__ ws,
    float* __restrict__ out)
{
    const int t = threadIdx.x;
    float term = 0.0f;
    if (t < kC) {
        float seg     = ws[WS_SEG + t];
        unsigned cnt  = reinterpret_cast<const unsigned*>(ws)[WS_CNT + t];
        float pix_num = (cnt == 0u) ? 1.0f : (float)cnt;
        term = lw[t] * seg / pix_num;
    }
#pragma unroll
    for (int off = 32; off > 0; off >>= 1)
        term += __shfl_down(term, off, 64);
    if (t == 0) {
        float loss_seg = term / (float)kC;
        float loss_dep = ws[WS_DEP] / (float)kNHW;
        // loss_*_begin are detached copies of the current losses (first call),
        // so this is x/x + y/y.
        out[0] = loss_seg / loss_seg + loss_dep / loss_dep;
    }
}

extern "C" void kernel_launch(void* const* d_in, const int* in_sizes, int n_in,
                              void* d_out, int out_size, void* d_ws, size_t ws_size,
                              hipStream_t stream) {
    const float* lw     = (const float*)d_in[0];
    const float* masks  = (const float*)d_in[1];
    const float* deps   = (const float*)d_in[2];
    const int*   tmasks = (const int*)d_in[3];
    const float* tdeps  = (const float*)d_in[4];
    float* ws  = (float*)d_ws;
    float* out = (float*)d_out;

    // ws is re-poisoned to 0xAA before every timed launch — zero the accumulators.
    hipMemsetAsync(d_ws, 0, (2 * kC + 1) * sizeof(float), stream);

    mtl_main<<<2048, 256, 0, stream>>>(masks, deps, tmasks, tdeps, ws);
    mtl_final<<<1, 64, 0, stream>>>(lw, ws, out);
}